// Round 4
// baseline (152.858 us; speedup 1.0000x reference)
//
#include <hip/hip_runtime.h>
#include <math.h>

#define NB 4
#define NN 10000
#define NE 160000
#define DIN 256   // C+H
#define DOUT 512  // 4H

typedef short bf16x8 __attribute__((ext_vector_type(8)));
typedef float f32x4 __attribute__((ext_vector_type(4)));

#define GLOAD_LDS16(g, l) \
    __builtin_amdgcn_global_load_lds((const __attribute__((address_space(1))) void*)(g), \
                                     (__attribute__((address_space(3))) void*)(l), 16, 0, 0)

__device__ inline unsigned short f2bf(float f) {
    unsigned int u = __float_as_uint(f);
    unsigned int r = (u + 0x7fffu + ((u >> 16) & 1u)) >> 16;
    return (unsigned short)r;
}
__device__ inline float bf2f(unsigned short u) {
    return __uint_as_float(((unsigned int)u) << 16);
}

// ---------------- pack W^T bf16 [512][256] + degree accumulation ----------------
// blocks 0..511: pack; blocks 512..1136: degcnt (deg/cnt pre-zeroed by memset)
__global__ __launch_bounds__(256) void k_packdeg(
        const float* __restrict__ Wi, const float* __restrict__ Wf,
        const float* __restrict__ Wo, const float* __restrict__ Wg,
        const float* __restrict__ bi, const float* __restrict__ bf,
        const float* __restrict__ bo, const float* __restrict__ bg,
        const int* __restrict__ ei, const float* __restrict__ ew,
        float* __restrict__ deg, int* __restrict__ cnt,
        unsigned short* __restrict__ Wt, float* __restrict__ bcat) {
    int bid = blockIdx.x;
    if (bid < 512) {
        int i = bid * 256 + threadIdx.x;  // 0..131071
        int n = i >> 8, k = i & 255;
        int g = n >> 7, j = n & 127;
        const float* W = (g == 0) ? Wi : (g == 1) ? Wf : (g == 2) ? Wo : Wg;
        Wt[i] = f2bf(W[k * 128 + j]);
        if (i < DOUT) {
            int gg = i >> 7, jj = i & 127;
            const float* bb = (gg == 0) ? bi : (gg == 1) ? bf : (gg == 2) ? bo : bg;
            bcat[i] = bb[jj];
        }
    } else {
        int e = (bid - 512) * 256 + threadIdx.x;  // exactly 160000
        int dst = ei[NE + e];
        atomicAdd(&deg[dst], ew[e]);
        atomicAdd(&cnt[dst], 1);
    }
}

// block 0: dinv = rsqrt(deg+1) (self-loop folded) + single-block scan of cnt
// blocks 1..1250: x||h -> bf16 batch-major xhb[b*NN+n][256]
__global__ __launch_bounds__(1024) void k_scancvt(
        float* __restrict__ deg, const int* __restrict__ cnt, int* __restrict__ offsets,
        const float* __restrict__ x, const float* __restrict__ h,
        unsigned short* __restrict__ xhb) {
    int t = threadIdx.x;
    int bid = blockIdx.x;
    if (bid == 0) {
        for (int i = t; i < NN; i += 1024) {
            deg[i] = rsqrtf(deg[i] + 1.0f);
        }
        __shared__ int wsum[16];
        int base = t * 10;
        int loc[10];
        int s = 0;
#pragma unroll
        for (int i = 0; i < 10; ++i) {
            int idx = base + i;
            int v = (idx < NN) ? cnt[idx] : 0;
            loc[i] = s;
            s += v;
        }
        int lane = t & 63, w = t >> 6;
        int inc = s;
        for (int o = 1; o < 64; o <<= 1) {
            int u = __shfl_up(inc, o);
            if (lane >= o) inc += u;
        }
        if (lane == 63) wsum[w] = inc;
        __syncthreads();
        if (t < 16) {
            int v = wsum[t];
            for (int o = 1; o < 16; o <<= 1) {
                int u = __shfl_up(v, o);
                if (t >= o) v += u;
            }
            wsum[t] = v;
        }
        __syncthreads();
        int wave_excl = (w > 0) ? wsum[w - 1] : 0;
        int thread_excl = wave_excl + inc - s;
#pragma unroll
        for (int i = 0; i < 10; ++i) {
            int idx = base + i;
            if (idx < NN) offsets[idx] = thread_excl + loc[i];
        }
        if (t == 0) offsets[NN] = wsum[15];
    } else {
        int id = (bid - 1) * 1024 + t;  // 0 .. 1,279,999
        int f8 = id * 8;
        int row = f8 >> 8;        // b*NN + n
        int col = f8 & 255;
        const float* src = ((col >> 7) ? h : x) + (size_t)row * 128 + (col & 127);
        float4 v0 = *(const float4*)src;
        float4 v1 = *(const float4*)(src + 4);
        bf16x8 o;
        o[0] = (short)f2bf(v0.x); o[1] = (short)f2bf(v0.y);
        o[2] = (short)f2bf(v0.z); o[3] = (short)f2bf(v0.w);
        o[4] = (short)f2bf(v1.x); o[5] = (short)f2bf(v1.y);
        o[6] = (short)f2bf(v1.z); o[7] = (short)f2bf(v1.w);
        *(bf16x8*)(xhb + (size_t)f8) = o;
    }
}

__global__ __launch_bounds__(256) void k_fill(const int* __restrict__ ei,
                                              const float* __restrict__ ew,
                                              const float* __restrict__ dinv,
                                              const int* __restrict__ offsets,
                                              int* cursor, int2* __restrict__ ebuf) {
    int e = blockIdx.x * 256 + threadIdx.x;  // exactly 160000
    int src = ei[e], dst = ei[NE + e];
    float norm = dinv[src] * ew[e] * dinv[dst];
    int pos = offsets[dst] + atomicAdd(&cursor[dst], 1);
    ebuf[pos] = make_int2(src, __float_as_int(norm));
}

// ---------------- aggregation: wave per (node, batch), XCD-pinned by batch ----------------
// bid&7 -> XCD; batch = xcd>>1, half = xcd&1. Each XCD works one batch's 5MB slab (L2-resident).
__global__ __launch_bounds__(256) void k_agg(const unsigned short* __restrict__ xhb,
                                             const float* __restrict__ dinv,
                                             const int* __restrict__ offsets,
                                             const int2* __restrict__ ebuf,
                                             unsigned short* __restrict__ aggb) {
    int t = threadIdx.x;
    int lane = t & 63, wid = t >> 6;
    int bid = blockIdx.x;        // 0..9999
    int xcd = bid & 7;
    int b = xcd >> 1, half = xcd & 1;
    int idx = bid >> 3;          // 0..1249
    int n = half * 5000 + idx * 4 + wid;

    const unsigned short* base = xhb + (size_t)b * NN * 256 + lane * 4;
    float a0 = 0.f, a1 = 0.f, a2 = 0.f, a3 = 0.f;

#define EACC(E)                                                       \
    {                                                                 \
        float w = __int_as_float((E).y);                              \
        ushort4 v = *(const ushort4*)(base + (size_t)(E).x * 256);    \
        a0 = fmaf(w, bf2f(v.x), a0);                                  \
        a1 = fmaf(w, bf2f(v.y), a1);                                  \
        a2 = fmaf(w, bf2f(v.z), a2);                                  \
        a3 = fmaf(w, bf2f(v.w), a3);                                  \
    }

    int beg = offsets[n], end = offsets[n + 1];
    int j = beg;
    for (; j + 8 <= end; j += 8) {
        int2 e0 = ebuf[j + 0], e1 = ebuf[j + 1], e2 = ebuf[j + 2], e3 = ebuf[j + 3];
        int2 e4 = ebuf[j + 4], e5 = ebuf[j + 5], e6 = ebuf[j + 6], e7 = ebuf[j + 7];
        EACC(e0); EACC(e1); EACC(e2); EACC(e3);
        EACC(e4); EACC(e5); EACC(e6); EACC(e7);
    }
    for (; j < end; ++j) {
        int2 e = ebuf[j];
        EACC(e);
    }
    {   // self loop
        float di = dinv[n];
        float w = di * di;
        ushort4 v = *(const ushort4*)(base + (size_t)n * 256);
        a0 = fmaf(w, bf2f(v.x), a0);
        a1 = fmaf(w, bf2f(v.y), a1);
        a2 = fmaf(w, bf2f(v.z), a2);
        a3 = fmaf(w, bf2f(v.w), a3);
    }
    ushort4 o;
    o.x = f2bf(a0); o.y = f2bf(a1); o.z = f2bf(a2); o.w = f2bf(a3);
    *(ushort4*)(aggb + ((size_t)b * NN + n) * 256 + lane * 4) = o;
}

// ---------------- MFMA GEMM (40000x256 @ 256^T x 512) + fused LSTM gates ----------------
// 256 thr / 4 waves, BM=32 rows. A staged ONCE (16KB LDS, XOR-swizzled via source), B in
// registers (wave owns 16-j slice x 4 gates x K=256 = 128 VGPR), 2 j-phases, 1 barrier.
__global__ __launch_bounds__(256) void k_gemm(const unsigned short* __restrict__ aggb,
                                              const unsigned short* __restrict__ Wt,
                                              const float* __restrict__ bcat,
                                              const float* __restrict__ c_in,
                                              float* __restrict__ out) {
    __shared__ __align__(16) unsigned short sA[32 * 256];
    int t = threadIdx.x;
    int lane = t & 63, wid = t >> 6;
    int lr = lane & 15, lk = lane >> 4;
    int rowbase = blockIdx.x * 32;

    // stage A: 32 rows x 512B, swizzled global source -> linear LDS
#pragma unroll
    for (int i = 0; i < 4; ++i) {
        int idx = i * 256 + t;
        int row = idx >> 5;
        int cb = (idx & 31) << 4;
        const char* g = (const char*)aggb + (size_t)(rowbase + row) * 512 + (cb ^ ((row & 7) << 4));
        char* l = (char*)sA + (size_t)(i * 256 + wid * 64) * 16;
        GLOAD_LDS16(g, l);
    }

    for (int ph = 0; ph < 2; ++ph) {
        int jbase = ph * 64 + wid * 16;
        // B fragments to registers (from L2-hot Wt)
        bf16x8 breg[4][8];
#pragma unroll
        for (int g = 0; g < 4; ++g)
#pragma unroll
            for (int kb = 0; kb < 8; ++kb)
                breg[g][kb] = *(const bf16x8*)(Wt + (size_t)(g * 128 + jbase + lr) * 256 + kb * 32 + lk * 8);

        int j = jbase + lr;
        float bi = bcat[j], bfv = bcat[128 + j], bo = bcat[256 + j], bg = bcat[384 + j];
        float cv[2][4];
#pragma unroll
        for (int mi = 0; mi < 2; ++mi)
#pragma unroll
            for (int r = 0; r < 4; ++r)
                cv[mi][r] = c_in[(size_t)(rowbase + mi * 16 + lk * 4 + r) * 128 + j];

        if (ph == 0) __syncthreads();  // A resident (drains stage + this phase's B loads)

        f32x4 acc[2][4];
#pragma unroll
        for (int mi = 0; mi < 2; ++mi)
#pragma unroll
            for (int g = 0; g < 4; ++g) acc[mi][g] = (f32x4)0.f;

#pragma unroll
        for (int kb = 0; kb < 8; ++kb) {
#pragma unroll
            for (int mi = 0; mi < 2; ++mi) {
                int arow = mi * 16 + lr;
                bf16x8 a = *(const bf16x8*)((const char*)sA + arow * 512 +
                                            (((kb << 6) + (lk << 4)) ^ ((lr & 7) << 4)));
                acc[mi][0] = __builtin_amdgcn_mfma_f32_16x16x32_bf16(a, breg[0][kb], acc[mi][0], 0, 0, 0);
                acc[mi][1] = __builtin_amdgcn_mfma_f32_16x16x32_bf16(a, breg[1][kb], acc[mi][1], 0, 0, 0);
                acc[mi][2] = __builtin_amdgcn_mfma_f32_16x16x32_bf16(a, breg[2][kb], acc[mi][2], 0, 0, 0);
                acc[mi][3] = __builtin_amdgcn_mfma_f32_16x16x32_bf16(a, breg[3][kb], acc[mi][3], 0, 0, 0);
            }
        }

        // fused LSTM epilogue
#pragma unroll
        for (int mi = 0; mi < 2; ++mi) {
#pragma unroll
            for (int r = 0; r < 4; ++r) {
                int row = rowbase + mi * 16 + lk * 4 + r;
                float vi = acc[mi][0][r] + bi;
                float vf = acc[mi][1][r] + bfv;
                float vo = acc[mi][2][r] + bo;
                float vg = acc[mi][3][r] + bg;
                float ig = 1.f / (1.f + __expf(-vi));
                float fg = 1.f / (1.f + __expf(-vf));
                float og = 1.f / (1.f + __expf(-vo));
                float gg = 1.f - 2.f / (__expf(2.f * vg) + 1.f);
                float cn = fg * cv[mi][r] + ig * gg;
                float tc = 1.f - 2.f / (__expf(2.f * cn) + 1.f);
                size_t o = (size_t)row * 128 + j;
                out[o] = og * tc;
                out[(size_t)NB * NN * 128 + o] = cn;
            }
        }
    }
}

// ---------------- launch ----------------

extern "C" void kernel_launch(void* const* d_in, const int* in_sizes, int n_in,
                              void* d_out, int out_size, void* d_ws, size_t ws_size,
                              hipStream_t stream) {
    const float* x = (const float*)d_in[0];
    const float* h = (const float*)d_in[1];
    const float* c = (const float*)d_in[2];
    const int* ei = (const int*)d_in[3];
    const float* ew = (const float*)d_in[4];
    const float* Wi = (const float*)d_in[5];
    const float* bi = (const float*)d_in[6];
    const float* Wf = (const float*)d_in[7];
    const float* bf = (const float*)d_in[8];
    const float* Wo = (const float*)d_in[9];
    const float* bo = (const float*)d_in[10];
    const float* Wg = (const float*)d_in[11];
    const float* bg = (const float*)d_in[12];
    float* out = (float*)d_out;

    char* ws = (char*)d_ws;
    size_t off = 0;
    auto alloc = [&](size_t bytes) {
        void* p = ws + off;
        off = (off + bytes + 255) & ~(size_t)255;
        return p;
    };
    float* deg = (float*)alloc((size_t)NN * 4);    // 40192B padded; becomes dinv
    int* cnt = (int*)alloc((size_t)NN * 4);        // 40192B
    int* cursor = (int*)alloc((size_t)NN * 4);     // 40192B  (deg,cnt,cursor contiguous)
    int* offsets = (int*)alloc((size_t)(NN + 1) * 4);
    float* bcat = (float*)alloc((size_t)DOUT * 4);
    unsigned short* Wt = (unsigned short*)alloc((size_t)DOUT * DIN * 2);
    int2* ebuf = (int2*)alloc((size_t)NE * 8);
    unsigned short* xhb = (unsigned short*)alloc((size_t)NB * NN * DIN * 2);   // [b*NN+n][256]
    unsigned short* aggb = (unsigned short*)alloc((size_t)NB * NN * DIN * 2);  // [b*NN+n][256]

    hipMemsetAsync(deg, 0, 3 * 40192, stream);  // deg, cnt, cursor -> 0

    hipLaunchKernelGGL(k_packdeg, dim3(1137), dim3(256), 0, stream,
                       Wi, Wf, Wo, Wg, bi, bf, bo, bg, ei, ew, deg, cnt, Wt, bcat);
    hipLaunchKernelGGL(k_scancvt, dim3(1251), dim3(1024), 0, stream,
                       deg, cnt, offsets, x, h, xhb);
    hipLaunchKernelGGL(k_fill, dim3(625), dim3(256), 0, stream,
                       ei, ew, deg, offsets, cursor, ebuf);
    hipLaunchKernelGGL(k_agg, dim3(10000), dim3(256), 0, stream,
                       xhb, deg, offsets, ebuf, aggb);
    hipLaunchKernelGGL(k_gemm, dim3(1250), dim3(256), 0, stream,
                       aggb, Wt, bcat, c, out);
}

// Round 5
// 143.829 us; speedup vs baseline: 1.0628x; 1.0628x over previous
//
#include <hip/hip_runtime.h>
#include <math.h>

#define NB 4
#define NN 10000
#define NE 160000
#define DIN 256   // C+H
#define DOUT 512  // 4H

typedef short bf16x8 __attribute__((ext_vector_type(8)));
typedef float f32x4 __attribute__((ext_vector_type(4)));

#define GLOAD_LDS16(g, l) \
    __builtin_amdgcn_global_load_lds((const __attribute__((address_space(1))) void*)(g), \
                                     (__attribute__((address_space(3))) void*)(l), 16, 0, 0)

__device__ inline unsigned short f2bf(float f) {
    unsigned int u = __float_as_uint(f);
    unsigned int r = (u + 0x7fffu + ((u >> 16) & 1u)) >> 16;
    return (unsigned short)r;
}
__device__ inline float bf2f(unsigned short u) {
    return __uint_as_float(((unsigned int)u) << 16);
}

// ---------------- pack W^T bf16 [512][256] + degree accumulation ----------------
__global__ __launch_bounds__(256) void k_packdeg(
        const float* __restrict__ Wi, const float* __restrict__ Wf,
        const float* __restrict__ Wo, const float* __restrict__ Wg,
        const float* __restrict__ bi, const float* __restrict__ bf,
        const float* __restrict__ bo, const float* __restrict__ bg,
        const int* __restrict__ ei, const float* __restrict__ ew,
        float* __restrict__ deg, int* __restrict__ cnt,
        unsigned short* __restrict__ Wt, float* __restrict__ bcat) {
    int bid = blockIdx.x;
    if (bid < 512) {
        int i = bid * 256 + threadIdx.x;  // 0..131071
        int n = i >> 8, k = i & 255;
        int g = n >> 7, j = n & 127;
        const float* W = (g == 0) ? Wi : (g == 1) ? Wf : (g == 2) ? Wo : Wg;
        Wt[i] = f2bf(W[k * 128 + j]);
        if (i < DOUT) {
            int gg = i >> 7, jj = i & 127;
            const float* bb = (gg == 0) ? bi : (gg == 1) ? bf : (gg == 2) ? bo : bg;
            bcat[i] = bb[jj];
        }
    } else {
        int e = (bid - 512) * 256 + threadIdx.x;  // exactly 160000
        int dst = ei[NE + e];
        atomicAdd(&deg[dst], ew[e]);
        atomicAdd(&cnt[dst], 1);
    }
}

// block 0: dinv = rsqrt(deg+1) + single-block scan of cnt
// blocks 1..1250: x||h -> bf16 NODE-major xhb[n*4+b][256]
__global__ __launch_bounds__(1024) void k_scancvt(
        float* __restrict__ deg, const int* __restrict__ cnt, int* __restrict__ offsets,
        const float* __restrict__ x, const float* __restrict__ h,
        unsigned short* __restrict__ xhb) {
    int t = threadIdx.x;
    int bid = blockIdx.x;
    if (bid == 0) {
        for (int i = t; i < NN; i += 1024) {
            deg[i] = rsqrtf(deg[i] + 1.0f);
        }
        __shared__ int wsum[16];
        int base = t * 10;
        int loc[10];
        int s = 0;
#pragma unroll
        for (int i = 0; i < 10; ++i) {
            int idx = base + i;
            int v = (idx < NN) ? cnt[idx] : 0;
            loc[i] = s;
            s += v;
        }
        int lane = t & 63, w = t >> 6;
        int inc = s;
        for (int o = 1; o < 64; o <<= 1) {
            int u = __shfl_up(inc, o);
            if (lane >= o) inc += u;
        }
        if (lane == 63) wsum[w] = inc;
        __syncthreads();
        if (t < 16) {
            int v = wsum[t];
            for (int o = 1; o < 16; o <<= 1) {
                int u = __shfl_up(v, o);
                if (t >= o) v += u;
            }
            wsum[t] = v;
        }
        __syncthreads();
        int wave_excl = (w > 0) ? wsum[w - 1] : 0;
        int thread_excl = wave_excl + inc - s;
#pragma unroll
        for (int i = 0; i < 10; ++i) {
            int idx = base + i;
            if (idx < NN) offsets[idx] = thread_excl + loc[i];
        }
        if (t == 0) offsets[NN] = wsum[15];
    } else {
        int id = (bid - 1) * 1024 + t;  // 0 .. 1,279,999
        int f8 = id * 8;
        int row = f8 >> 8;        // n*4 + b
        int col = f8 & 255;
        int n = row >> 2, b = row & 3;
        const float* src = ((col >> 7) ? h : x) + ((size_t)b * NN + n) * 128 + (col & 127);
        float4 v0 = *(const float4*)src;
        float4 v1 = *(const float4*)(src + 4);
        bf16x8 o;
        o[0] = (short)f2bf(v0.x); o[1] = (short)f2bf(v0.y);
        o[2] = (short)f2bf(v0.z); o[3] = (short)f2bf(v0.w);
        o[4] = (short)f2bf(v1.x); o[5] = (short)f2bf(v1.y);
        o[6] = (short)f2bf(v1.z); o[7] = (short)f2bf(v1.w);
        *(bf16x8*)(xhb + (size_t)f8) = o;
    }
}

__global__ __launch_bounds__(256) void k_fill(const int* __restrict__ ei,
                                              const float* __restrict__ ew,
                                              const float* __restrict__ dinv,
                                              const int* __restrict__ offsets,
                                              int* cursor, int2* __restrict__ ebuf) {
    int e = blockIdx.x * 256 + threadIdx.x;  // exactly 160000
    int src = ei[e], dst = ei[NE + e];
    float norm = dinv[src] * ew[e] * dinv[dst];
    int pos = offsets[dst] + atomicAdd(&cursor[dst], 1);
    ebuf[pos] = make_int2(src, __float_as_int(norm));
}

// ---------------- aggregation: one wave per node, all 4 batches ----------------
// lane l: batch b = l>>4, k-range ks = (l&15)*16 (16 bf16 = 32B = 2 b128 loads)
// per edge: ONE contiguous 2KB gather from node-major xhb[src*1024 ..]
__global__ __launch_bounds__(256) void k_agg(const unsigned short* __restrict__ xhb,
                                             const float* __restrict__ dinv,
                                             const int* __restrict__ offsets,
                                             const int2* __restrict__ ebuf,
                                             unsigned short* __restrict__ aggb) {
    int t = threadIdx.x;
    int lane = t & 63, wid = t >> 6;
    int n = blockIdx.x * 4 + wid;
    int b = lane >> 4;
    int ks = (lane & 15) << 4;
    int l16 = lane * 16;

    float acc[16];
#pragma unroll
    for (int i = 0; i < 16; ++i) acc[i] = 0.f;

#define EACC(E)                                                         \
    {                                                                   \
        float w = __int_as_float((E).y);                                \
        const unsigned short* p = xhb + (size_t)(E).x * 1024 + l16;     \
        bf16x8 v0 = *(const bf16x8*)p;                                  \
        bf16x8 v1 = *(const bf16x8*)(p + 8);                            \
        acc[0] = fmaf(w, bf2f((unsigned short)v0[0]), acc[0]);          \
        acc[1] = fmaf(w, bf2f((unsigned short)v0[1]), acc[1]);          \
        acc[2] = fmaf(w, bf2f((unsigned short)v0[2]), acc[2]);          \
        acc[3] = fmaf(w, bf2f((unsigned short)v0[3]), acc[3]);          \
        acc[4] = fmaf(w, bf2f((unsigned short)v0[4]), acc[4]);          \
        acc[5] = fmaf(w, bf2f((unsigned short)v0[5]), acc[5]);          \
        acc[6] = fmaf(w, bf2f((unsigned short)v0[6]), acc[6]);          \
        acc[7] = fmaf(w, bf2f((unsigned short)v0[7]), acc[7]);          \
        acc[8] = fmaf(w, bf2f((unsigned short)v1[0]), acc[8]);          \
        acc[9] = fmaf(w, bf2f((unsigned short)v1[1]), acc[9]);          \
        acc[10] = fmaf(w, bf2f((unsigned short)v1[2]), acc[10]);        \
        acc[11] = fmaf(w, bf2f((unsigned short)v1[3]), acc[11]);        \
        acc[12] = fmaf(w, bf2f((unsigned short)v1[4]), acc[12]);        \
        acc[13] = fmaf(w, bf2f((unsigned short)v1[5]), acc[13]);        \
        acc[14] = fmaf(w, bf2f((unsigned short)v1[6]), acc[14]);        \
        acc[15] = fmaf(w, bf2f((unsigned short)v1[7]), acc[15]);        \
    }

    int beg = offsets[n], end = offsets[n + 1];
    int j = beg;
    for (; j + 4 <= end; j += 4) {
        int2 e0 = ebuf[j + 0], e1 = ebuf[j + 1], e2 = ebuf[j + 2], e3 = ebuf[j + 3];
        EACC(e0); EACC(e1); EACC(e2); EACC(e3);
    }
    for (; j < end; ++j) {
        int2 e = ebuf[j];
        EACC(e);
    }
    {   // self loop: weight dinv[n]^2
        float di = dinv[n];
        int2 es = make_int2(n, __float_as_int(di * di));
        EACC(es);
    }
    bf16x8 o0, o1;
#pragma unroll
    for (int i = 0; i < 8; ++i) { o0[i] = (short)f2bf(acc[i]); o1[i] = (short)f2bf(acc[8 + i]); }
    unsigned short* dst = aggb + ((size_t)b * NN + n) * 256 + ks;
    *(bf16x8*)dst = o0;
    *(bf16x8*)(dst + 8) = o1;
}

// ---------------- MFMA GEMM (40000x256 @ 256^T x 512) + fused LSTM gates ----------------
// grid 2500 = 625 row-blocks x 4 j-blocks. Block: 64 rows x 32 j x 4 gates.
// B (128 Wt-rows x 256 k = 64KB) staged in LDS once (source-preswizzled), ONE barrier.
// A-frags direct from global with next-kb prefetch. Wave = 32 rows x 16 j x 4 gates.
__global__ __launch_bounds__(256) void k_gemm(const unsigned short* __restrict__ aggb,
                                              const unsigned short* __restrict__ Wt,
                                              const float* __restrict__ bcat,
                                              const float* __restrict__ c_in,
                                              float* __restrict__ out) {
    __shared__ __align__(16) unsigned short sB[128 * 256];  // 64KB: lrow = g*32 + jl
    int t = threadIdx.x;
    int lane = t & 63, wid = t >> 6;
    int wr = wid >> 1, wjg = wid & 1;
    int lr = lane & 15, lk = lane >> 4;
    int bid = blockIdx.x;
    int rb = bid >> 2, jb = bid & 3;
    int rowbase = rb * 64;
    int jbase = jb * 32;

    // stage B: 128 lrows x 512B = 4096 16B-chunks; lrow g*32+jl <-> Wt row g*128+jbase+jl
#pragma unroll
    for (int i = 0; i < 16; ++i) {
        int idx = i * 256 + t;
        int lrow = idx >> 5;
        int off = (idx & 31) << 4;
        int wtrow = ((lrow >> 5) << 7) + jbase + (lrow & 31);
        const char* g = (const char*)Wt + (size_t)wtrow * 512 + (off ^ ((lrow & 7) << 4));
        char* l = (char*)sB + (size_t)(i * 256 + wid * 64) * 16;
        GLOAD_LDS16(g, l);
    }

    // A-frag pointers: row = rowbase + wr*32 + mi*16 + lr, k-slice lk*8
    const unsigned short* A0 = aggb + (size_t)(rowbase + wr * 32 + lr) * 256 + lk * 8;
    const unsigned short* A1 = A0 + 16 * 256;

    // prefetch c_in + biases (before barrier; drained by it)
    int j = jbase + wjg * 16 + lr;
    float b_i = bcat[j], b_f = bcat[128 + j], b_o = bcat[256 + j], b_g = bcat[384 + j];
    float cv[2][4];
#pragma unroll
    for (int mi = 0; mi < 2; ++mi)
#pragma unroll
        for (int r = 0; r < 4; ++r)
            cv[mi][r] = c_in[(size_t)(rowbase + wr * 32 + mi * 16 + lk * 4 + r) * 128 + j];

    // first A prefetch
    bf16x8 a0c = *(const bf16x8*)A0;
    bf16x8 a1c = *(const bf16x8*)A1;

    __syncthreads();  // B resident

    f32x4 acc[2][4];
#pragma unroll
    for (int mi = 0; mi < 2; ++mi)
#pragma unroll
        for (int g = 0; g < 4; ++g) acc[mi][g] = (f32x4)0.f;

    // B ds_read byte address helper: lrow = g*32 + wjg*16 + lr
#define BADDR(g, kb) ((size_t)(((g) * 32 + wjg * 16 + lr) * 512 + \
                      ((((kb) << 6) + (lk << 4)) ^ (((wjg * 16 + lr) & 7) << 4))))

#pragma unroll
    for (int kb = 0; kb < 8; ++kb) {
        bf16x8 a0 = a0c, a1 = a1c;
        if (kb < 7) {
            a0c = *(const bf16x8*)(A0 + (kb + 1) * 32);
            a1c = *(const bf16x8*)(A1 + (kb + 1) * 32);
        }
        bf16x8 b0 = *(const bf16x8*)((const char*)sB + BADDR(0, kb));
        bf16x8 b1 = *(const bf16x8*)((const char*)sB + BADDR(1, kb));
        bf16x8 b2 = *(const bf16x8*)((const char*)sB + BADDR(2, kb));
        bf16x8 b3 = *(const bf16x8*)((const char*)sB + BADDR(3, kb));
        acc[0][0] = __builtin_amdgcn_mfma_f32_16x16x32_bf16(a0, b0, acc[0][0], 0, 0, 0);
        acc[0][1] = __builtin_amdgcn_mfma_f32_16x16x32_bf16(a0, b1, acc[0][1], 0, 0, 0);
        acc[0][2] = __builtin_amdgcn_mfma_f32_16x16x32_bf16(a0, b2, acc[0][2], 0, 0, 0);
        acc[0][3] = __builtin_amdgcn_mfma_f32_16x16x32_bf16(a0, b3, acc[0][3], 0, 0, 0);
        acc[1][0] = __builtin_amdgcn_mfma_f32_16x16x32_bf16(a1, b0, acc[1][0], 0, 0, 0);
        acc[1][1] = __builtin_amdgcn_mfma_f32_16x16x32_bf16(a1, b1, acc[1][1], 0, 0, 0);
        acc[1][2] = __builtin_amdgcn_mfma_f32_16x16x32_bf16(a1, b2, acc[1][2], 0, 0, 0);
        acc[1][3] = __builtin_amdgcn_mfma_f32_16x16x32_bf16(a1, b3, acc[1][3], 0, 0, 0);
    }

    // fused LSTM epilogue: lane holds i/f/o/g for (row, j)
#pragma unroll
    for (int mi = 0; mi < 2; ++mi) {
#pragma unroll
        for (int r = 0; r < 4; ++r) {
            int row = rowbase + wr * 32 + mi * 16 + lk * 4 + r;
            float vi = acc[mi][0][r] + b_i;
            float vf = acc[mi][1][r] + b_f;
            float vo = acc[mi][2][r] + b_o;
            float vg = acc[mi][3][r] + b_g;
            float ig = 1.f / (1.f + __expf(-vi));
            float fg = 1.f / (1.f + __expf(-vf));
            float og = 1.f / (1.f + __expf(-vo));
            float gg = 1.f - 2.f / (__expf(2.f * vg) + 1.f);
            float cn = fg * cv[mi][r] + ig * gg;
            float tc = 1.f - 2.f / (__expf(2.f * cn) + 1.f);
            size_t o = (size_t)row * 128 + j;
            out[o] = og * tc;
            out[(size_t)NB * NN * 128 + o] = cn;
        }
    }
}

// ---------------- launch ----------------

extern "C" void kernel_launch(void* const* d_in, const int* in_sizes, int n_in,
                              void* d_out, int out_size, void* d_ws, size_t ws_size,
                              hipStream_t stream) {
    const float* x = (const float*)d_in[0];
    const float* h = (const float*)d_in[1];
    const float* c = (const float*)d_in[2];
    const int* ei = (const int*)d_in[3];
    const float* ew = (const float*)d_in[4];
    const float* Wi = (const float*)d_in[5];
    const float* bi = (const float*)d_in[6];
    const float* Wf = (const float*)d_in[7];
    const float* bf = (const float*)d_in[8];
    const float* Wo = (const float*)d_in[9];
    const float* bo = (const float*)d_in[10];
    const float* Wg = (const float*)d_in[11];
    const float* bg = (const float*)d_in[12];
    float* out = (float*)d_out;

    char* ws = (char*)d_ws;
    size_t off = 0;
    auto alloc = [&](size_t bytes) {
        void* p = ws + off;
        off = (off + bytes + 255) & ~(size_t)255;
        return p;
    };
    float* deg = (float*)alloc((size_t)NN * 4);    // 40192B padded; becomes dinv
    int* cnt = (int*)alloc((size_t)NN * 4);        // 40192B
    int* cursor = (int*)alloc((size_t)NN * 4);     // 40192B  (deg,cnt,cursor contiguous)
    int* offsets = (int*)alloc((size_t)(NN + 1) * 4);
    float* bcat = (float*)alloc((size_t)DOUT * 4);
    unsigned short* Wt = (unsigned short*)alloc((size_t)DOUT * DIN * 2);
    int2* ebuf = (int2*)alloc((size_t)NE * 8);
    unsigned short* xhb = (unsigned short*)alloc((size_t)NN * 4 * DIN * 2);    // node-major [n][b][k]
    unsigned short* aggb = (unsigned short*)alloc((size_t)NB * NN * DIN * 2);  // batch-major [b*NN+n][k]

    hipMemsetAsync(deg, 0, 3 * 40192, stream);  // deg, cnt, cursor -> 0

    hipLaunchKernelGGL(k_packdeg, dim3(1137), dim3(256), 0, stream,
                       Wi, Wf, Wo, Wg, bi, bf, bo, bg, ei, ew, deg, cnt, Wt, bcat);
    hipLaunchKernelGGL(k_scancvt, dim3(1251), dim3(1024), 0, stream,
                       deg, cnt, offsets, x, h, xhb);
    hipLaunchKernelGGL(k_fill, dim3(625), dim3(256), 0, stream,
                       ei, ew, deg, offsets, cursor, ebuf);
    hipLaunchKernelGGL(k_agg, dim3(2500), dim3(256), 0, stream,
                       xhb, deg, offsets, ebuf, aggb);
    hipLaunchKernelGGL(k_gemm, dim3(2500), dim3(256), 0, stream,
                       aggb, Wt, bcat, c, out);
}

// Round 6
// 139.777 us; speedup vs baseline: 1.0936x; 1.0290x over previous
//
#include <hip/hip_runtime.h>
#include <math.h>

#define NB 4
#define NN 10000
#define NE 160000
#define DIN 256   // C+H
#define DOUT 512  // 4H

typedef short bf16x8 __attribute__((ext_vector_type(8)));
typedef float f32x4 __attribute__((ext_vector_type(4)));

#define GLOAD_LDS16(g, l) \
    __builtin_amdgcn_global_load_lds((const __attribute__((address_space(1))) void*)(g), \
                                     (__attribute__((address_space(3))) void*)(l), 16, 0, 0)

__device__ inline unsigned short f2bf(float f) {
    unsigned int u = __float_as_uint(f);
    unsigned int r = (u + 0x7fffu + ((u >> 16) & 1u)) >> 16;
    return (unsigned short)r;
}
__device__ inline float bf2f(unsigned short u) {
    return __uint_as_float(((unsigned int)u) << 16);
}

// ---------------- pack W^T bf16 [512][256] + degree accumulation ----------------
__global__ __launch_bounds__(256) void k_packdeg(
        const float* __restrict__ Wi, const float* __restrict__ Wf,
        const float* __restrict__ Wo, const float* __restrict__ Wg,
        const float* __restrict__ bi, const float* __restrict__ bf,
        const float* __restrict__ bo, const float* __restrict__ bg,
        const int* __restrict__ ei, const float* __restrict__ ew,
        float* __restrict__ deg, int* __restrict__ cnt,
        unsigned short* __restrict__ Wt, float* __restrict__ bcat) {
    int bid = blockIdx.x;
    if (bid < 512) {
        int i = bid * 256 + threadIdx.x;  // 0..131071
        int n = i >> 8, k = i & 255;
        int g = n >> 7, j = n & 127;
        const float* W = (g == 0) ? Wi : (g == 1) ? Wf : (g == 2) ? Wo : Wg;
        Wt[i] = f2bf(W[k * 128 + j]);
        if (i < DOUT) {
            int gg = i >> 7, jj = i & 127;
            const float* bb = (gg == 0) ? bi : (gg == 1) ? bf : (gg == 2) ? bo : bg;
            bcat[i] = bb[jj];
        }
    } else {
        int e = (bid - 512) * 256 + threadIdx.x;  // exactly 160000
        int dst = ei[NE + e];
        atomicAdd(&deg[dst], ew[e]);
        atomicAdd(&cnt[dst], 1);
    }
}

// block 0: dinv = rsqrt(deg+1) + single-block scan of cnt
// blocks 1..1250: x||h -> bf16 NODE-major xhb[n*4+b][256]
__global__ __launch_bounds__(1024) void k_scancvt(
        float* __restrict__ deg, const int* __restrict__ cnt, int* __restrict__ offsets,
        const float* __restrict__ x, const float* __restrict__ h,
        unsigned short* __restrict__ xhb) {
    int t = threadIdx.x;
    int bid = blockIdx.x;
    if (bid == 0) {
        for (int i = t; i < NN; i += 1024) {
            deg[i] = rsqrtf(deg[i] + 1.0f);
        }
        __shared__ int wsum[16];
        int base = t * 10;
        int loc[10];
        int s = 0;
#pragma unroll
        for (int i = 0; i < 10; ++i) {
            int idx = base + i;
            int v = (idx < NN) ? cnt[idx] : 0;
            loc[i] = s;
            s += v;
        }
        int lane = t & 63, w = t >> 6;
        int inc = s;
        for (int o = 1; o < 64; o <<= 1) {
            int u = __shfl_up(inc, o);
            if (lane >= o) inc += u;
        }
        if (lane == 63) wsum[w] = inc;
        __syncthreads();
        if (t < 16) {
            int v = wsum[t];
            for (int o = 1; o < 16; o <<= 1) {
                int u = __shfl_up(v, o);
                if (t >= o) v += u;
            }
            wsum[t] = v;
        }
        __syncthreads();
        int wave_excl = (w > 0) ? wsum[w - 1] : 0;
        int thread_excl = wave_excl + inc - s;
#pragma unroll
        for (int i = 0; i < 10; ++i) {
            int idx = base + i;
            if (idx < NN) offsets[idx] = thread_excl + loc[i];
        }
        if (t == 0) offsets[NN] = wsum[15];
    } else {
        int id = (bid - 1) * 1024 + t;  // 0 .. 1,279,999
        int f8 = id * 8;
        int row = f8 >> 8;        // n*4 + b
        int col = f8 & 255;
        int n = row >> 2, b = row & 3;
        const float* src = ((col >> 7) ? h : x) + ((size_t)b * NN + n) * 128 + (col & 127);
        float4 v0 = *(const float4*)src;
        float4 v1 = *(const float4*)(src + 4);
        bf16x8 o;
        o[0] = (short)f2bf(v0.x); o[1] = (short)f2bf(v0.y);
        o[2] = (short)f2bf(v0.z); o[3] = (short)f2bf(v0.w);
        o[4] = (short)f2bf(v1.x); o[5] = (short)f2bf(v1.y);
        o[6] = (short)f2bf(v1.z); o[7] = (short)f2bf(v1.w);
        *(bf16x8*)(xhb + (size_t)f8) = o;
    }
}

__global__ __launch_bounds__(256) void k_fill(const int* __restrict__ ei,
                                              const float* __restrict__ ew,
                                              const float* __restrict__ dinv,
                                              const int* __restrict__ offsets,
                                              int* cursor, int2* __restrict__ ebuf) {
    int e = blockIdx.x * 256 + threadIdx.x;  // exactly 160000
    int src = ei[e], dst = ei[NE + e];
    float norm = dinv[src] * ew[e] * dinv[dst];
    int pos = offsets[dst] + atomicAdd(&cursor[dst], 1);
    ebuf[pos] = make_int2(src, __float_as_int(norm));
}

// ---------------- aggregation: one wave per node, all 4 batches ----------------
__global__ __launch_bounds__(256) void k_agg(const unsigned short* __restrict__ xhb,
                                             const float* __restrict__ dinv,
                                             const int* __restrict__ offsets,
                                             const int2* __restrict__ ebuf,
                                             unsigned short* __restrict__ aggb) {
    int t = threadIdx.x;
    int lane = t & 63, wid = t >> 6;
    int n = blockIdx.x * 4 + wid;
    int b = lane >> 4;
    int ks = (lane & 15) << 4;
    int l16 = lane * 16;

    float acc[16];
#pragma unroll
    for (int i = 0; i < 16; ++i) acc[i] = 0.f;

#define EACC(E)                                                         \
    {                                                                   \
        float w = __int_as_float((E).y);                                \
        const unsigned short* p = xhb + (size_t)(E).x * 1024 + l16;     \
        bf16x8 v0 = *(const bf16x8*)p;                                  \
        bf16x8 v1 = *(const bf16x8*)(p + 8);                            \
        acc[0] = fmaf(w, bf2f((unsigned short)v0[0]), acc[0]);          \
        acc[1] = fmaf(w, bf2f((unsigned short)v0[1]), acc[1]);          \
        acc[2] = fmaf(w, bf2f((unsigned short)v0[2]), acc[2]);          \
        acc[3] = fmaf(w, bf2f((unsigned short)v0[3]), acc[3]);          \
        acc[4] = fmaf(w, bf2f((unsigned short)v0[4]), acc[4]);          \
        acc[5] = fmaf(w, bf2f((unsigned short)v0[5]), acc[5]);          \
        acc[6] = fmaf(w, bf2f((unsigned short)v0[6]), acc[6]);          \
        acc[7] = fmaf(w, bf2f((unsigned short)v0[7]), acc[7]);          \
        acc[8] = fmaf(w, bf2f((unsigned short)v1[0]), acc[8]);          \
        acc[9] = fmaf(w, bf2f((unsigned short)v1[1]), acc[9]);          \
        acc[10] = fmaf(w, bf2f((unsigned short)v1[2]), acc[10]);        \
        acc[11] = fmaf(w, bf2f((unsigned short)v1[3]), acc[11]);        \
        acc[12] = fmaf(w, bf2f((unsigned short)v1[4]), acc[12]);        \
        acc[13] = fmaf(w, bf2f((unsigned short)v1[5]), acc[13]);        \
        acc[14] = fmaf(w, bf2f((unsigned short)v1[6]), acc[14]);        \
        acc[15] = fmaf(w, bf2f((unsigned short)v1[7]), acc[15]);        \
    }

    int beg = offsets[n], end = offsets[n + 1];
    int j = beg;
    for (; j + 4 <= end; j += 4) {
        int2 e0 = ebuf[j + 0], e1 = ebuf[j + 1], e2 = ebuf[j + 2], e3 = ebuf[j + 3];
        EACC(e0); EACC(e1); EACC(e2); EACC(e3);
    }
    for (; j < end; ++j) {
        int2 e = ebuf[j];
        EACC(e);
    }
    {   // self loop: weight dinv[n]^2
        float di = dinv[n];
        int2 es = make_int2(n, __float_as_int(di * di));
        EACC(es);
    }
    bf16x8 o0, o1;
#pragma unroll
    for (int i = 0; i < 8; ++i) { o0[i] = (short)f2bf(acc[i]); o1[i] = (short)f2bf(acc[8 + i]); }
    unsigned short* dst = aggb + ((size_t)b * NN + n) * 256 + ks;
    *(bf16x8*)dst = o0;
    *(bf16x8*)(dst + 8) = o1;
}

// ---------------- MFMA GEMM (40000x256 @ 256^T x 512) + fused LSTM gates ----------------
// Persistent-B: grid 2048 = 32 s x 8 j x 8 xcd; valid blocks cover 250 chunks x 8 j-slices.
// Block (128 thr / 2 waves): stages its j-slice's B (64 Wt rows = 32KB, K-major layout) ONCE,
// then sweeps 160 rows in 5 x 32-row iterations with register-double-buffered A and c_in.
// All 8 j-slices of a chunk land on the same XCD (bid&7) -> A rows fetched once per XCD.
__global__ __launch_bounds__(128) void k_gemm(const unsigned short* __restrict__ aggb,
                                              const unsigned short* __restrict__ Wt,
                                              const float* __restrict__ bcat,
                                              const float* __restrict__ c_in,
                                              float* __restrict__ out) {
    __shared__ __align__(16) unsigned short sB[64 * 256];  // 32KB, K-major: [kb][lk][g][lr]x16B
    int t = threadIdx.x;
    int lane = t & 63, w = t >> 6;
    int lr = lane & 15, lk = lane >> 4;
    int bid = blockIdx.x;
    int x = bid & 7;
    int jb = (bid >> 3) & 7;
    int s = bid >> 6;  // 0..31
    int chunk;
    if (x < 2) {
        chunk = x * 32 + s;
    } else {
        if (s >= 31) return;
        chunk = 64 + (x - 2) * 31 + s;
    }
    int rowchunk = chunk * 160;

    // stage B: 2048 16B chunks; m = i*128 + t -> (kb,lk,g,lr)
#pragma unroll
    for (int i = 0; i < 16; ++i) {
        int m = i * 128 + t;
        int kb_ = m >> 8, lk_ = (m >> 6) & 3, g_ = (m >> 4) & 3, lr_ = m & 15;
        const char* gp = (const char*)Wt + (size_t)(g_ * 128 + jb * 16 + lr_) * 512 + kb_ * 64 + lk_ * 16;
        char* lp = (char*)sB + (size_t)(i * 128 + w * 64) * 16;
        GLOAD_LDS16(gp, lp);
    }

    const unsigned short* Aptr = aggb + (size_t)(rowchunk + w * 16 + lr) * 256 + lk * 8;
    const char* Bbase = (const char*)sB + lk * 1024 + lr * 16;
    int j = jb * 16 + lr;
    float b_i = bcat[j], b_f = bcat[128 + j], b_o = bcat[256 + j], b_g = bcat[384 + j];
    const float* Cptr = c_in + (size_t)(rowchunk + w * 16 + lk * 4) * 128 + j;

    bf16x8 aA[8], aB_[8];
    float cvA[4], cvB[4];
#pragma unroll
    for (int kb = 0; kb < 8; ++kb) aA[kb] = *(const bf16x8*)(Aptr + kb * 32);
#pragma unroll
    for (int r = 0; r < 4; ++r) cvA[r] = Cptr[(size_t)r * 128];

    __syncthreads();  // B resident (drains all gload_lds)

#define GITER(IT, CUR, NXT, CVC, CVN) {                                                      \
    if ((IT) < 4) {                                                                          \
        _Pragma("unroll")                                                                    \
        for (int kb = 0; kb < 8; ++kb)                                                       \
            NXT[kb] = *(const bf16x8*)(Aptr + (size_t)((IT) + 1) * 32 * 256 + kb * 32);      \
        _Pragma("unroll")                                                                    \
        for (int r = 0; r < 4; ++r)                                                          \
            CVN[r] = Cptr[(size_t)(((IT) + 1) * 32 + r) * 128];                              \
    }                                                                                        \
    f32x4 ac0 = (f32x4)0.f, ac1 = (f32x4)0.f, ac2 = (f32x4)0.f, ac3 = (f32x4)0.f;            \
    _Pragma("unroll")                                                                        \
    for (int kb = 0; kb < 8; ++kb) {                                                         \
        bf16x8 b0 = *(const bf16x8*)(Bbase + kb * 4096 + 0 * 256);                           \
        bf16x8 b1 = *(const bf16x8*)(Bbase + kb * 4096 + 1 * 256);                           \
        bf16x8 b2 = *(const bf16x8*)(Bbase + kb * 4096 + 2 * 256);                           \
        bf16x8 b3 = *(const bf16x8*)(Bbase + kb * 4096 + 3 * 256);                           \
        ac0 = __builtin_amdgcn_mfma_f32_16x16x32_bf16(CUR[kb], b0, ac0, 0, 0, 0);            \
        ac1 = __builtin_amdgcn_mfma_f32_16x16x32_bf16(CUR[kb], b1, ac1, 0, 0, 0);            \
        ac2 = __builtin_amdgcn_mfma_f32_16x16x32_bf16(CUR[kb], b2, ac2, 0, 0, 0);            \
        ac3 = __builtin_amdgcn_mfma_f32_16x16x32_bf16(CUR[kb], b3, ac3, 0, 0, 0);            \
    }                                                                                        \
    _Pragma("unroll")                                                                        \
    for (int r = 0; r < 4; ++r) {                                                            \
        float vi = ac0[r] + b_i, vf = ac1[r] + b_f, vo = ac2[r] + b_o, vg = ac3[r] + b_g;    \
        float ig = 1.f / (1.f + __expf(-vi));                                                \
        float fg = 1.f / (1.f + __expf(-vf));                                                \
        float og = 1.f / (1.f + __expf(-vo));                                                \
        float gg = 1.f - 2.f / (__expf(2.f * vg) + 1.f);                                     \
        float cn = fg * CVC[r] + ig * gg;                                                    \
        float tc = 1.f - 2.f / (__expf(2.f * cn) + 1.f);                                     \
        size_t o = (size_t)(rowchunk + (IT) * 32 + w * 16 + lk * 4 + r) * 128 + j;           \
        out[o] = og * tc;                                                                    \
        out[(size_t)NB * NN * 128 + o] = cn;                                                 \
    } }

    GITER(0, aA, aB_, cvA, cvB);
    GITER(1, aB_, aA, cvB, cvA);
    GITER(2, aA, aB_, cvA, cvB);
    GITER(3, aB_, aA, cvB, cvA);
    GITER(4, aA, aB_, cvA, cvB);
}

// ---------------- launch ----------------

extern "C" void kernel_launch(void* const* d_in, const int* in_sizes, int n_in,
                              void* d_out, int out_size, void* d_ws, size_t ws_size,
                              hipStream_t stream) {
    const float* x = (const float*)d_in[0];
    const float* h = (const float*)d_in[1];
    const float* c = (const float*)d_in[2];
    const int* ei = (const int*)d_in[3];
    const float* ew = (const float*)d_in[4];
    const float* Wi = (const float*)d_in[5];
    const float* bi = (const float*)d_in[6];
    const float* Wf = (const float*)d_in[7];
    const float* bf = (const float*)d_in[8];
    const float* Wo = (const float*)d_in[9];
    const float* bo = (const float*)d_in[10];
    const float* Wg = (const float*)d_in[11];
    const float* bg = (const float*)d_in[12];
    float* out = (float*)d_out;

    char* ws = (char*)d_ws;
    size_t off = 0;
    auto alloc = [&](size_t bytes) {
        void* p = ws + off;
        off = (off + bytes + 255) & ~(size_t)255;
        return p;
    };
    float* deg = (float*)alloc((size_t)NN * 4);    // 40192B padded; becomes dinv
    int* cnt = (int*)alloc((size_t)NN * 4);        // 40192B
    int* cursor = (int*)alloc((size_t)NN * 4);     // 40192B  (deg,cnt,cursor contiguous)
    int* offsets = (int*)alloc((size_t)(NN + 1) * 4);
    float* bcat = (float*)alloc((size_t)DOUT * 4);
    unsigned short* Wt = (unsigned short*)alloc((size_t)DOUT * DIN * 2);
    int2* ebuf = (int2*)alloc((size_t)NE * 8);
    unsigned short* xhb = (unsigned short*)alloc((size_t)NN * 4 * DIN * 2);    // node-major [n][b][k]
    unsigned short* aggb = (unsigned short*)alloc((size_t)NB * NN * DIN * 2);  // batch-major [b*NN+n][k]

    hipMemsetAsync(deg, 0, 3 * 40192, stream);  // deg, cnt, cursor -> 0

    hipLaunchKernelGGL(k_packdeg, dim3(1137), dim3(256), 0, stream,
                       Wi, Wf, Wo, Wg, bi, bf, bo, bg, ei, ew, deg, cnt, Wt, bcat);
    hipLaunchKernelGGL(k_scancvt, dim3(1251), dim3(1024), 0, stream,
                       deg, cnt, offsets, x, h, xhb);
    hipLaunchKernelGGL(k_fill, dim3(625), dim3(256), 0, stream,
                       ei, ew, deg, offsets, cursor, ebuf);
    hipLaunchKernelGGL(k_agg, dim3(2500), dim3(256), 0, stream,
                       xhb, deg, offsets, ebuf, aggb);
    hipLaunchKernelGGL(k_gemm, dim3(2048), dim3(128), 0, stream,
                       aggb, Wt, bcat, c, out);
}